// Round 18
// baseline (33.955 us; speedup 1.0000x reference)
//
#include <hip/hip_runtime.h>

// ODEDriftIntegrator: Euler step (validated R17: truncation ~5e-4, absmax
// 0.015625 vs threshold 5.2e-2) + diffusion kick + weighted sum.
//
// R18 = R17 math untouched; SINGLE change: remove __launch_bounds__ and go
// grid 2048 (1 job/wave). Evidence: R17 regression gives fixed F ~16us with
// all pipes idle and OccupancyPercent 22% (~1.75 waves/SIMD effective);
// VGPR demand is only 68, so hardware could hold ~7 waves/SIMD, but the
// launch_bounds waves-per-eu attribute has been pinning ~3 since R12 (also
// explains R12==R14 grid-experiment flatness). Removing the cap lets the
// allocator/no-attr default give natural residency; 8192 waves x exactly
// 1 job each.
//
// Pipeline (validated): job = 16 outputs, lane carries 5 independent Euler
// chains; layer2 mfma_f32_16x16x32_f16 with A-permutation
// j_of(t,i)=32(t>>1)+8(i>>2)+4(t&1)+(i&3) so tanh'd layer2 outputs form the
// W3-MFMA B-frag k-set (shuffle-free epilogue, y replicated f32); 4-op
// packed-f16 half-sigmoid tanh (VOP3P clamp); MFMA-computed colsum/b3
// folds; zero atomics, zero LDS, zero barriers.

typedef __attribute__((ext_vector_type(2))) __fp16 h2;
typedef __attribute__((ext_vector_type(8))) __fp16 h8;
typedef __attribute__((ext_vector_type(4))) float f32x4;

#define NOUT   131072
#define NJOBS  (NOUT / 16)           // 8192 jobs of 16 outputs x 5 chains

// packed-half constants (both halves identical) -- halved validated quartic
#define C0H 0x3B913B91u  //  0.9458   (= 1.8916/2)
#define C1H 0xB996B996u  // -0.69824  (= -1.3965/2)
#define HALFC 0x38003800u//  0.5

__device__ __forceinline__ unsigned u_of(h2 x) { return __builtin_bit_cast(unsigned, x); }
__device__ __forceinline__ unsigned pkrtz_u(float a, float b) {
  return u_of(__builtin_amdgcn_cvt_pkrtz(a, b));
}
__device__ __forceinline__ unsigned pk_fma_vvv(unsigned a, unsigned b, unsigned c) {
  unsigned d; asm("v_pk_fma_f16 %0, %1, %2, %3" : "=v"(d) : "v"(a), "v"(b), "v"(c)); return d;
}
__device__ __forceinline__ unsigned pk_fma_vvs(unsigned a, unsigned b, unsigned cs) {
  unsigned d; asm("v_pk_fma_f16 %0, %1, %2, %3" : "=v"(d) : "v"(a), "v"(b), "s"(cs)); return d;
}
__device__ __forceinline__ unsigned pk_fma_clamp_vvs(unsigned a, unsigned b, unsigned cs) {
  unsigned d; asm("v_pk_fma_f16 %0, %1, %2, %3 clamp" : "=v"(d) : "v"(a), "v"(b), "s"(cs)); return d;
}
__device__ __forceinline__ unsigned pk_mul_vv(unsigned a, unsigned b) {
  unsigned d; asm("v_pk_mul_f16 %0, %1, %2" : "=v"(d) : "v"(a), "v"(b)); return d;
}
// 4-op half-sigmoid: q = clamp01(0.5 + s*(c0h + c1h*w + c2h*w^2)), w=s*s.
__device__ __forceinline__ unsigned tanh4(unsigned s, unsigned c2v) {
  unsigned w = pk_mul_vv(s, s);
  unsigned p = pk_fma_vvs(c2v, w, C1H);
  p = pk_fma_vvs(p, w, C0H);
  return pk_fma_clamp_vvs(s, p, HALFC);
}

union HU { unsigned u[4]; h8 v; };

__global__ void ode_mfma_kernel(
    const float* __restrict__ sigmap,  // [NPTS,3]
    const float* __restrict__ Wpp,     // [NPTS]
    const float* __restrict__ W1p,     // [2,64]
    const float* __restrict__ b1p,     // [64]
    const float* __restrict__ W2p,     // [64,64]
    const float* __restrict__ b2p,     // [64]
    const float* __restrict__ W3p,     // [64,1]
    const float* __restrict__ b3p,     // [1]
    float* __restrict__ outp)          // [131072]
{
  const int lane = threadIdx.x & 63;
  const int col  = lane & 15;   // output slot within job (B-col == D-col)
  const int g    = lane >> 4;   // lane group (k-group / D-row group)
  const int wid  = blockIdx.x * (blockDim.x >> 6) + (threadIdx.x >> 6);
  const int nw   = gridDim.x * (blockDim.x >> 6);   // 8192

  // pinned VGPR for c2h = 0.20898 packed
  unsigned c2v; asm("v_mov_b32 %0, 0x32B032B0" : "=v"(c2v));

  // out-hidden j for (tile t, row i) -- R8/R15-validated permutation
  auto j_of = [](int t, int i) {
    return 32 * (t >> 1) + 8 * (i >> 2) + 4 * (t & 1) + (i & 3);
  };

  // ---- persistent per-lane constants (no LDS, no barrier) ----
  unsigned w10u[8], w11u[8], b01u[8];
#pragma unroll
  for (int ee = 0; ee < 8; ++ee) {
    int j0 = (ee < 4) ? (8 * g + 2 * ee) : (32 + 8 * g + 2 * (ee - 4));
    w10u[ee] = pkrtz_u(0.5f * W1p[j0],      0.5f * W1p[j0 + 1]);
    w11u[ee] = pkrtz_u(0.5f * W1p[64 + j0], 0.5f * W1p[64 + j0 + 1]);
    b01u[ee] = pkrtz_u(0.5f * b1p[j0],      0.5f * b1p[j0 + 1]);
  }
  // layer2 A-frags: A[row=col][k] = W2[k][j_of(t,col)] RAW (sigmoid fold).
  HU afr[4][2];
#pragma unroll
  for (int t = 0; t < 4; ++t) {
    int jc = j_of(t, col);
#pragma unroll
    for (int kt = 0; kt < 2; ++kt)
#pragma unroll
      for (int ee = 0; ee < 4; ++ee) {
        int k0 = kt * 32 + 8 * g + 2 * ee;
        afr[t][kt].u[ee] = pkrtz_u(W2p[(k0)     * 64 + jc],
                                   W2p[(k0 + 1) * 64 + jc]);
      }
  }
  // broadcast(-0.5) B-operand for the column-sum MFMAs
  HU nhf;
#pragma unroll
  for (int ee = 0; ee < 4; ++ee) nhf.u[ee] = 0xB800B800u;

  // layer2 C-init via matrix pipe: D = 0.5*(b2[j_of] - colsum[j_of]).
  f32x4 cinit[4];
#pragma unroll
  for (int t = 0; t < 4; ++t) {
    f32x4 c;
#pragma unroll
    for (int r = 0; r < 4; ++r) c[r] = 0.5f * b2p[j_of(t, 4 * g + r)];
    c = __builtin_amdgcn_mfma_f32_16x16x32_f16(afr[t][0].v, nhf.v, c, 0, 0, 0);
    c = __builtin_amdgcn_mfma_f32_16x16x32_f16(afr[t][1].v, nhf.v, c, 0, 0, 0);
    cinit[t] = c;
  }
  // W3-MFMA A-frags (broadcast rows): A2[*][k] = 2*W3[k] (sigmoid fold).
  HU afr2[2];
#pragma unroll
  for (int kt = 0; kt < 2; ++kt)
#pragma unroll
    for (int ee = 0; ee < 4; ++ee) {
      int k0 = kt * 32 + 8 * g + 2 * ee;
      afr2[kt].u[ee] = pkrtz_u(2.0f * W3p[k0], 2.0f * W3p[k0 + 1]);
    }
  // b3v = b3 - sum(W3), on the matrix pipe.
  float b3s = b3p[0];
  f32x4 y0 = {b3s, b3s, b3s, b3s};
  y0 = __builtin_amdgcn_mfma_f32_16x16x32_f16(afr2[0].v, nhf.v, y0, 0, 0, 0);
  y0 = __builtin_amdgcn_mfma_f32_16x16x32_f16(afr2[1].v, nhf.v, y0, 0, 0, 0);
  const float b3v = y0[0];

  // one job = 16 outputs x 5 independent Euler chains (chain-major).
#pragma unroll 1
  for (int job = wid; job < NJOBS; job += nw) {
    const int pbase = job * 80 + 5 * col;
    float yacc = 0.0f;
#pragma unroll
    for (int s = 0; s < 5; ++s) {
      const int p = pbase + s;
      const float xs = sigmap[3 * p + 0];
      const float us = sigmap[3 * p + 1];
      const unsigned uhs = pkrtz_u(us, us);
      const unsigned xh  = pkrtz_u(xs, xs);
      // layer1
      HU b0, b1;
#pragma unroll
      for (int ee = 0; ee < 4; ++ee) {
        unsigned cv0 = pk_fma_vvv(uhs, w11u[ee],     b01u[ee]);
        unsigned cv1 = pk_fma_vvv(uhs, w11u[ee + 4], b01u[ee + 4]);
        b0.u[ee] = tanh4(pk_fma_vvv(xh, w10u[ee],     cv0), c2v);
        b1.u[ee] = tanh4(pk_fma_vvv(xh, w10u[ee + 4], cv1), c2v);
      }
      // layer2 MFMAs -> q2 frags (shuffle-free W3 epilogue layout)
      HU q2f[2];
#pragma unroll
      for (int tp = 0; tp < 2; ++tp) {
        f32x4 a0 = cinit[2 * tp], a1 = cinit[2 * tp + 1];
        a0 = __builtin_amdgcn_mfma_f32_16x16x32_f16(afr[2 * tp][0].v,     b0.v, a0, 0, 0, 0);
        a1 = __builtin_amdgcn_mfma_f32_16x16x32_f16(afr[2 * tp + 1][0].v, b0.v, a1, 0, 0, 0);
        a0 = __builtin_amdgcn_mfma_f32_16x16x32_f16(afr[2 * tp][1].v,     b1.v, a0, 0, 0, 0);
        a1 = __builtin_amdgcn_mfma_f32_16x16x32_f16(afr[2 * tp + 1][1].v, b1.v, a1, 0, 0, 0);
        q2f[tp].u[0] = tanh4(pkrtz_u(a0[0], a0[1]), c2v);
        q2f[tp].u[1] = tanh4(pkrtz_u(a0[2], a0[3]), c2v);
        q2f[tp].u[2] = tanh4(pkrtz_u(a1[0], a1[1]), c2v);
        q2f[tp].u[3] = tanh4(pkrtz_u(a1[2], a1[3]), c2v);
      }
      // layer3 on matrix pipe: f = drift, replicated in all lanes (f32).
      f32x4 yv = {b3v, b3v, b3v, b3v};
      yv = __builtin_amdgcn_mfma_f32_16x16x32_f16(afr2[0].v, q2f[0].v, yv, 0, 0, 0);
      yv = __builtin_amdgcn_mfma_f32_16x16x32_f16(afr2[1].v, q2f[1].v, yv, 0, 0, 0);
      // Euler + diffusion kick + weighted accumulate
      float xe = fmaf(0.01f, yv[0], xs);
      xe = fmaf(0.01f, sigmap[3 * p + 2], xe);  // sqrt(2*0.5*sigma^2*dt)=0.01
      yacc = fmaf(Wpp[p], xe, yacc);
    }
    if (lane < 16) outp[job * 16 + col] = yacc;
  }
}

extern "C" void kernel_launch(void* const* d_in, const int* in_sizes, int n_in,
                              void* d_out, int out_size, void* d_ws, size_t ws_size,
                              hipStream_t stream) {
  const float* sigmap = (const float*)d_in[0];
  const float* Wpp    = (const float*)d_in[1];
  const float* W1p    = (const float*)d_in[2];
  const float* b1p    = (const float*)d_in[3];
  const float* W2p    = (const float*)d_in[4];
  const float* b2p    = (const float*)d_in[5];
  const float* W3p    = (const float*)d_in[6];
  const float* b3p    = (const float*)d_in[7];
  float* outp = (float*)d_out;

  // 2048 blocks x 4 waves = 8192 waves = exactly 1 job/wave; residency now
  // limited by VGPR count (~68), not a waves-per-eu attribute.
  ode_mfma_kernel<<<2048, 256, 0, stream>>>(sigmap, Wpp, W1p, b1p, W2p, b2p,
                                            W3p, b3p, outp);
  (void)d_ws; (void)ws_size; (void)n_in; (void)in_sizes;
}

// Round 19
// 21.726 us; speedup vs baseline: 1.5629x; 1.5629x over previous
//
#include <hip/hip_runtime.h>

// ODEDriftIntegrator: Euler step (validated R17: truncation ~5e-4, absmax
// 0.015625 vs threshold 5.2e-2) + diffusion kick + weighted sum.
//
// R19 = R17 math + register budget, R12 grid: (256,3) [cap ~85 >= 68 demand,
// no spill -- R18 proved removing bounds lets the compiler pick 64 and
// spill] with grid 2048 -> 8192 waves = exactly 1 job/wave. At 68 VGPR the
// HW can hold ~7 waves/SIMD; R17's 1024-block grid queued only 4. Per-wave
// wall also drops (setup + 1 job, not setup + 2). This is the one untested
// cell of {grid x integrator}: R12 was this grid with midpoint.
//
// Pipeline (validated): job = 16 outputs, lane carries 5 independent Euler
// chains; layer2 mfma_f32_16x16x32_f16 with A-permutation
// j_of(t,i)=32(t>>1)+8(i>>2)+4(t&1)+(i&3) so tanh'd layer2 outputs form the
// W3-MFMA B-frag k-set (shuffle-free epilogue, y replicated f32); 4-op
// packed-f16 half-sigmoid tanh (VOP3P clamp); MFMA-computed colsum/b3
// folds; zero atomics, zero LDS, zero barriers.

typedef __attribute__((ext_vector_type(2))) __fp16 h2;
typedef __attribute__((ext_vector_type(8))) __fp16 h8;
typedef __attribute__((ext_vector_type(4))) float f32x4;

#define NOUT   131072
#define NJOBS  (NOUT / 16)           // 8192 jobs of 16 outputs x 5 chains

// packed-half constants (both halves identical) -- halved validated quartic
#define C0H 0x3B913B91u  //  0.9458   (= 1.8916/2)
#define C1H 0xB996B996u  // -0.69824  (= -1.3965/2)
#define HALFC 0x38003800u//  0.5

__device__ __forceinline__ unsigned u_of(h2 x) { return __builtin_bit_cast(unsigned, x); }
__device__ __forceinline__ unsigned pkrtz_u(float a, float b) {
  return u_of(__builtin_amdgcn_cvt_pkrtz(a, b));
}
__device__ __forceinline__ unsigned pk_fma_vvv(unsigned a, unsigned b, unsigned c) {
  unsigned d; asm("v_pk_fma_f16 %0, %1, %2, %3" : "=v"(d) : "v"(a), "v"(b), "v"(c)); return d;
}
__device__ __forceinline__ unsigned pk_fma_vvs(unsigned a, unsigned b, unsigned cs) {
  unsigned d; asm("v_pk_fma_f16 %0, %1, %2, %3" : "=v"(d) : "v"(a), "v"(b), "s"(cs)); return d;
}
__device__ __forceinline__ unsigned pk_fma_clamp_vvs(unsigned a, unsigned b, unsigned cs) {
  unsigned d; asm("v_pk_fma_f16 %0, %1, %2, %3 clamp" : "=v"(d) : "v"(a), "v"(b), "s"(cs)); return d;
}
__device__ __forceinline__ unsigned pk_mul_vv(unsigned a, unsigned b) {
  unsigned d; asm("v_pk_mul_f16 %0, %1, %2" : "=v"(d) : "v"(a), "v"(b)); return d;
}
// 4-op half-sigmoid: q = clamp01(0.5 + s*(c0h + c1h*w + c2h*w^2)), w=s*s.
__device__ __forceinline__ unsigned tanh4(unsigned s, unsigned c2v) {
  unsigned w = pk_mul_vv(s, s);
  unsigned p = pk_fma_vvs(c2v, w, C1H);
  p = pk_fma_vvs(p, w, C0H);
  return pk_fma_clamp_vvs(s, p, HALFC);
}

union HU { unsigned u[4]; h8 v; };

__global__ __launch_bounds__(256, 3) void ode_mfma_kernel(
    const float* __restrict__ sigmap,  // [NPTS,3]
    const float* __restrict__ Wpp,     // [NPTS]
    const float* __restrict__ W1p,     // [2,64]
    const float* __restrict__ b1p,     // [64]
    const float* __restrict__ W2p,     // [64,64]
    const float* __restrict__ b2p,     // [64]
    const float* __restrict__ W3p,     // [64,1]
    const float* __restrict__ b3p,     // [1]
    float* __restrict__ outp)          // [131072]
{
  const int lane = threadIdx.x & 63;
  const int col  = lane & 15;   // output slot within job (B-col == D-col)
  const int g    = lane >> 4;   // lane group (k-group / D-row group)
  const int wid  = blockIdx.x * (blockDim.x >> 6) + (threadIdx.x >> 6);
  const int nw   = gridDim.x * (blockDim.x >> 6);   // 8192

  // pinned VGPR for c2h = 0.20898 packed
  unsigned c2v; asm("v_mov_b32 %0, 0x32B032B0" : "=v"(c2v));

  // out-hidden j for (tile t, row i) -- R8/R15-validated permutation
  auto j_of = [](int t, int i) {
    return 32 * (t >> 1) + 8 * (i >> 2) + 4 * (t & 1) + (i & 3);
  };

  // ---- persistent per-lane constants (no LDS, no barrier) ----
  unsigned w10u[8], w11u[8], b01u[8];
#pragma unroll
  for (int ee = 0; ee < 8; ++ee) {
    int j0 = (ee < 4) ? (8 * g + 2 * ee) : (32 + 8 * g + 2 * (ee - 4));
    w10u[ee] = pkrtz_u(0.5f * W1p[j0],      0.5f * W1p[j0 + 1]);
    w11u[ee] = pkrtz_u(0.5f * W1p[64 + j0], 0.5f * W1p[64 + j0 + 1]);
    b01u[ee] = pkrtz_u(0.5f * b1p[j0],      0.5f * b1p[j0 + 1]);
  }
  // layer2 A-frags: A[row=col][k] = W2[k][j_of(t,col)] RAW (sigmoid fold).
  HU afr[4][2];
#pragma unroll
  for (int t = 0; t < 4; ++t) {
    int jc = j_of(t, col);
#pragma unroll
    for (int kt = 0; kt < 2; ++kt)
#pragma unroll
      for (int ee = 0; ee < 4; ++ee) {
        int k0 = kt * 32 + 8 * g + 2 * ee;
        afr[t][kt].u[ee] = pkrtz_u(W2p[(k0)     * 64 + jc],
                                   W2p[(k0 + 1) * 64 + jc]);
      }
  }
  // broadcast(-0.5) B-operand for the column-sum MFMAs
  HU nhf;
#pragma unroll
  for (int ee = 0; ee < 4; ++ee) nhf.u[ee] = 0xB800B800u;

  // layer2 C-init via matrix pipe: D = 0.5*(b2[j_of] - colsum[j_of]).
  f32x4 cinit[4];
#pragma unroll
  for (int t = 0; t < 4; ++t) {
    f32x4 c;
#pragma unroll
    for (int r = 0; r < 4; ++r) c[r] = 0.5f * b2p[j_of(t, 4 * g + r)];
    c = __builtin_amdgcn_mfma_f32_16x16x32_f16(afr[t][0].v, nhf.v, c, 0, 0, 0);
    c = __builtin_amdgcn_mfma_f32_16x16x32_f16(afr[t][1].v, nhf.v, c, 0, 0, 0);
    cinit[t] = c;
  }
  // W3-MFMA A-frags (broadcast rows): A2[*][k] = 2*W3[k] (sigmoid fold).
  HU afr2[2];
#pragma unroll
  for (int kt = 0; kt < 2; ++kt)
#pragma unroll
    for (int ee = 0; ee < 4; ++ee) {
      int k0 = kt * 32 + 8 * g + 2 * ee;
      afr2[kt].u[ee] = pkrtz_u(2.0f * W3p[k0], 2.0f * W3p[k0 + 1]);
    }
  // b3v = b3 - sum(W3), on the matrix pipe.
  float b3s = b3p[0];
  f32x4 y0 = {b3s, b3s, b3s, b3s};
  y0 = __builtin_amdgcn_mfma_f32_16x16x32_f16(afr2[0].v, nhf.v, y0, 0, 0, 0);
  y0 = __builtin_amdgcn_mfma_f32_16x16x32_f16(afr2[1].v, nhf.v, y0, 0, 0, 0);
  const float b3v = y0[0];

  // one job = 16 outputs x 5 independent Euler chains (chain-major).
#pragma unroll 1
  for (int job = wid; job < NJOBS; job += nw) {
    const int pbase = job * 80 + 5 * col;
    float yacc = 0.0f;
#pragma unroll
    for (int s = 0; s < 5; ++s) {
      const int p = pbase + s;
      const float xs = sigmap[3 * p + 0];
      const float us = sigmap[3 * p + 1];
      const unsigned uhs = pkrtz_u(us, us);
      const unsigned xh  = pkrtz_u(xs, xs);
      // layer1
      HU b0, b1;
#pragma unroll
      for (int ee = 0; ee < 4; ++ee) {
        unsigned cv0 = pk_fma_vvv(uhs, w11u[ee],     b01u[ee]);
        unsigned cv1 = pk_fma_vvv(uhs, w11u[ee + 4], b01u[ee + 4]);
        b0.u[ee] = tanh4(pk_fma_vvv(xh, w10u[ee],     cv0), c2v);
        b1.u[ee] = tanh4(pk_fma_vvv(xh, w10u[ee + 4], cv1), c2v);
      }
      // layer2 MFMAs -> q2 frags (shuffle-free W3 epilogue layout)
      HU q2f[2];
#pragma unroll
      for (int tp = 0; tp < 2; ++tp) {
        f32x4 a0 = cinit[2 * tp], a1 = cinit[2 * tp + 1];
        a0 = __builtin_amdgcn_mfma_f32_16x16x32_f16(afr[2 * tp][0].v,     b0.v, a0, 0, 0, 0);
        a1 = __builtin_amdgcn_mfma_f32_16x16x32_f16(afr[2 * tp + 1][0].v, b0.v, a1, 0, 0, 0);
        a0 = __builtin_amdgcn_mfma_f32_16x16x32_f16(afr[2 * tp][1].v,     b1.v, a0, 0, 0, 0);
        a1 = __builtin_amdgcn_mfma_f32_16x16x32_f16(afr[2 * tp + 1][1].v, b1.v, a1, 0, 0, 0);
        q2f[tp].u[0] = tanh4(pkrtz_u(a0[0], a0[1]), c2v);
        q2f[tp].u[1] = tanh4(pkrtz_u(a0[2], a0[3]), c2v);
        q2f[tp].u[2] = tanh4(pkrtz_u(a1[0], a1[1]), c2v);
        q2f[tp].u[3] = tanh4(pkrtz_u(a1[2], a1[3]), c2v);
      }
      // layer3 on matrix pipe: f = drift, replicated in all lanes (f32).
      f32x4 yv = {b3v, b3v, b3v, b3v};
      yv = __builtin_amdgcn_mfma_f32_16x16x32_f16(afr2[0].v, q2f[0].v, yv, 0, 0, 0);
      yv = __builtin_amdgcn_mfma_f32_16x16x32_f16(afr2[1].v, q2f[1].v, yv, 0, 0, 0);
      // Euler + diffusion kick + weighted accumulate
      float xe = fmaf(0.01f, yv[0], xs);
      xe = fmaf(0.01f, sigmap[3 * p + 2], xe);  // sqrt(2*0.5*sigma^2*dt)=0.01
      yacc = fmaf(Wpp[p], xe, yacc);
    }
    if (lane < 16) outp[job * 16 + col] = yacc;
  }
}

extern "C" void kernel_launch(void* const* d_in, const int* in_sizes, int n_in,
                              void* d_out, int out_size, void* d_ws, size_t ws_size,
                              hipStream_t stream) {
  const float* sigmap = (const float*)d_in[0];
  const float* Wpp    = (const float*)d_in[1];
  const float* W1p    = (const float*)d_in[2];
  const float* b1p    = (const float*)d_in[3];
  const float* W2p    = (const float*)d_in[4];
  const float* b2p    = (const float*)d_in[5];
  const float* W3p    = (const float*)d_in[6];
  const float* b3p    = (const float*)d_in[7];
  float* outp = (float*)d_out;

  // 2048 blocks x 4 waves = 8192 waves = exactly 1 job/wave; ~7 waves/SIMD
  // resident at 68 VGPR under (256,3).
  ode_mfma_kernel<<<2048, 256, 0, stream>>>(sigmap, Wpp, W1p, b1p, W2p, b2p,
                                            W3p, b3p, outp);
  (void)d_ws; (void)ws_size; (void)n_in; (void)in_sizes;
}